// Round 5
// baseline (133.823 us; speedup 1.0000x reference)
//
#include <hip/hip_runtime.h>
#include <hip/hip_bf16.h>
#include <hip/hip_cooperative_groups.h>

namespace cg = cooperative_groups;

#define BATCH 64
#define CDIM  256
#define MHW   196
#define MP    224      // padded K for covariance (multiple of 32)
#define EDIM  512
#define CC    65536    // CDIM*CDIM
#define NTRI  10       // upper-triangle 64x64 tiles of a 256x256 matrix

typedef __attribute__((ext_vector_type(8))) short short8_t;   // 8 x bf16 MFMA frag
typedef __attribute__((ext_vector_type(4))) float f32x4;
typedef __attribute__((ext_vector_type(4))) unsigned int u32x4;

static __device__ __forceinline__ short f2bf(float f) {
    __hip_bfloat16 h = __float2bfloat16(f);
    return (short)__builtin_bit_cast(unsigned short, h);
}

struct MMOp {
    const __hip_bfloat16* A;
    const __hip_bfloat16* B;
    const __hip_bfloat16* D;
    __hip_bfloat16*       out;
    const float*          alpha_ptr;
    int                   alpha_mode;
    float                 alpha_c, beta, gamma;
    float*                nrm;
};

// ---------------------------------------------------------------------------
// center_row: one wave centers one (b,c) row, bf16-cast (pad to MP), rowsq.
// ---------------------------------------------------------------------------
static __device__ __forceinline__ void center_row(
    const float* __restrict__ feat, __hip_bfloat16* __restrict__ xcb,
    float* __restrict__ rowsq, int row, int l)
{
    const float* src = feat + (size_t)row * MHW;
    float v0 = src[l];
    float v1 = src[l + 64];
    float v2 = src[l + 128];
    float v3 = (l + 192 < MHW) ? src[l + 192] : 0.0f;
    float s = v0 + v1 + v2 + v3;
    #pragma unroll
    for (int o = 32; o >= 1; o >>= 1) s += __shfl_xor(s, o, 64);
    const float mean = s * (1.0f / MHW);
    v0 -= mean; v1 -= mean; v2 -= mean;
    v3 = (l + 192 < MHW) ? (v3 - mean) : 0.0f;
    float sq = v0*v0 + v1*v1 + v2*v2 + v3*v3;
    #pragma unroll
    for (int o = 32; o >= 1; o >>= 1) sq += __shfl_xor(sq, o, 64);
    if (l == 0) rowsq[row] = sq;
    __hip_bfloat16* dst = xcb + (size_t)row * MP;
    dst[l]       = __float2bfloat16(v0);
    dst[l + 64]  = __float2bfloat16(v1);
    dst[l + 128] = __float2bfloat16(v2);
    if (l + 192 < MP) dst[l + 192] = __float2bfloat16(v3);   // zero pad
}

// ---------------------------------------------------------------------------
// mm_tile: one 64x64 upper-triangle tile (t in [0,NTRI)) of
// out = a*(A@B) + beta*D + gamma*I for batch b. B stored exactly symmetric
// (mirror writes) so row-reads give B^T columns. f32 accum, bf16 I/O.
// alpha_mode: a = alpha_c / sum_256(alpha_ptr[b*256..]).
// ---------------------------------------------------------------------------
template<int KT, bool NORM>
static __device__ __forceinline__ void mm_tile(
    const __hip_bfloat16* __restrict__ A, const __hip_bfloat16* __restrict__ Bm,
    const __hip_bfloat16* __restrict__ D, __hip_bfloat16* __restrict__ out,
    const float* __restrict__ alpha_ptr, int alpha_mode,
    float alpha_c, float beta, float gamma, float* __restrict__ nrm,
    int b, int t,
    __hip_bfloat16 (*As)[72], __hip_bfloat16 (*Bs)[72],
    float* red, float* s_alpha)
{
    int ti, tj;
    if (t < 4)      { ti = 0; tj = t; }
    else if (t < 7) { ti = 1; tj = t - 3; }
    else if (t < 9) { ti = 2; tj = t - 5; }
    else            { ti = 3; tj = 3; }

    const int tid = threadIdx.x;
    const int wv = tid >> 6, l = tid & 63;
    const int wr = wv >> 1, wc = wv & 1;
    const int lr = l & 15,  lg = l >> 4;

    __syncthreads();   // WAR guard vs previous phase's LDS readers
    if (alpha_mode) {
        float v = alpha_ptr[b * 256 + tid];
        #pragma unroll
        for (int o = 32; o >= 1; o >>= 1) v += __shfl_xor(v, o, 64);
        if (l == 0) red[wv] = v;
        __syncthreads();
        if (tid == 0) *s_alpha = alpha_c / (red[0] + red[1] + red[2] + red[3]);
    } else if (tid == 0) {
        *s_alpha = alpha_c;
    }

    const __hip_bfloat16* Ab = A  + (size_t)b * (CDIM * KT) + (size_t)ti * 64 * KT;
    const __hip_bfloat16* Bb = Bm + (size_t)b * (CDIM * KT) + (size_t)tj * 64 * KT;

    f32x4 acc[2][2];
    #pragma unroll
    for (int i = 0; i < 2; i++)
        #pragma unroll
        for (int j = 0; j < 2; j++)
            #pragma unroll
            for (int r = 0; r < 4; r++) acc[i][j][r] = 0.0f;

    #pragma unroll
    for (int k0 = 0; k0 < KT; k0 += 64) {
        const int kw   = (KT - k0 >= 64) ? 64 : (KT - k0);   // 64 or 32
        const int segs = kw >> 3;                            // 8 or 4
        __syncthreads();
        for (int u = tid; u < 64 * segs; u += 256) {
            const int row = u / segs;
            const int seg = u - row * segs;
            *reinterpret_cast<u32x4*>(&As[row][seg * 8]) =
                *reinterpret_cast<const u32x4*>(Ab + (size_t)row * KT + k0 + seg * 8);
            *reinterpret_cast<u32x4*>(&Bs[row][seg * 8]) =
                *reinterpret_cast<const u32x4*>(Bb + (size_t)row * KT + k0 + seg * 8);
        }
        __syncthreads();
        const int nks = kw >> 5;   // 2 or 1
        for (int ks = 0; ks < nks; ks++) {
            short8_t af[2], bfr[2];
            #pragma unroll
            for (int i = 0; i < 2; i++)
                af[i] = *reinterpret_cast<const short8_t*>(&As[wr * 32 + i * 16 + lr][ks * 32 + lg * 8]);
            #pragma unroll
            for (int j = 0; j < 2; j++)
                bfr[j] = *reinterpret_cast<const short8_t*>(&Bs[wc * 32 + j * 16 + lr][ks * 32 + lg * 8]);
            #pragma unroll
            for (int i = 0; i < 2; i++)
                #pragma unroll
                for (int j = 0; j < 2; j++)
                    acc[i][j] = __builtin_amdgcn_mfma_f32_16x16x32_bf16(af[i], bfr[j], acc[i][j], 0, 0, 0);
        }
    }

    const float a = *s_alpha;   // ordered by the staging __syncthreads above
    __hip_bfloat16* ob = out + (size_t)b * CC;
    const __hip_bfloat16* Db = D ? (D + (size_t)b * CC) : nullptr;
    float ns = 0.0f;
    #pragma unroll
    for (int i = 0; i < 2; i++) {
        #pragma unroll
        for (int j = 0; j < 2; j++) {
            #pragma unroll
            for (int r = 0; r < 4; r++) {
                const int grow = ti * 64 + wr * 32 + i * 16 + lg * 4 + r;
                const int gcol = tj * 64 + wc * 32 + j * 16 + lr;
                float v = a * acc[i][j][r];
                if (Db) v += beta * __bfloat162float(Db[grow * 256 + gcol]);
                if (grow == gcol) v += gamma;
                const __hip_bfloat16 hv = __float2bfloat16(v);
                ob[grow * 256 + gcol] = hv;
                if (ti != tj) ob[gcol * 256 + grow] = hv;   // exact-symmetry mirror
                if (NORM) {
                    const float fv = __bfloat162float(hv);
                    ns += ((ti != tj) ? 2.0f : 1.0f) * fv * fv;
                }
            }
        }
    }
    if constexpr (NORM) {
        #pragma unroll
        for (int o = 32; o >= 1; o >>= 1) ns += __shfl_xor(ns, o, 64);
        __syncthreads();
        if (l == 0) red[wv] = ns;
        __syncthreads();
        if (tid == 0) nrm[b * NTRI + t] = red[0] + red[1] + red[2] + red[3];
    }
}

// ---------------------------------------------------------------------------
// proj_body: split-K MFMA projection piece for (ks in [0,64), et in [0,8)).
// Block K-chunk 1024 (4 waves x 256), cross-wave LDS reduce -> upart[ks].
// ---------------------------------------------------------------------------
static __device__ __forceinline__ void proj_body(
    const __hip_bfloat16* __restrict__ flat, const float* __restrict__ W,
    float* __restrict__ upart, int ks, int et, float (*racc)[64][65])
{
    const int tid = threadIdx.x, wv = tid >> 6, l = tid & 63;
    const int lr = l & 15, lg = l >> 4;
    const int kbase = ks * 1024 + wv * 256;

    f32x4 acc[4][4];
    #pragma unroll
    for (int i = 0; i < 4; i++)
        #pragma unroll
        for (int j = 0; j < 4; j++)
            #pragma unroll
            for (int r = 0; r < 4; r++) acc[i][j][r] = 0.0f;

    for (int kk = 0; kk < 256; kk += 32) {
        const int k = kbase + kk + lg * 8;
        short8_t af[4];
        #pragma unroll
        for (int i = 0; i < 4; i++)
            af[i] = *reinterpret_cast<const short8_t*>(flat + (size_t)(i * 16 + lr) * CC + k);
        short8_t bfr[4];
        #pragma unroll
        for (int j = 0; j < 4; j++) {
            const f32x4* wp = reinterpret_cast<const f32x4*>(W + (size_t)(et * 64 + j * 16 + lr) * CC + k);
            const f32x4 w0 = wp[0], w1 = wp[1];
            short8_t s;
            s[0] = f2bf(w0[0]); s[1] = f2bf(w0[1]); s[2] = f2bf(w0[2]); s[3] = f2bf(w0[3]);
            s[4] = f2bf(w1[0]); s[5] = f2bf(w1[1]); s[6] = f2bf(w1[2]); s[7] = f2bf(w1[3]);
            bfr[j] = s;
        }
        #pragma unroll
        for (int i = 0; i < 4; i++)
            #pragma unroll
            for (int j = 0; j < 4; j++)
                acc[i][j] = __builtin_amdgcn_mfma_f32_16x16x32_bf16(af[i], bfr[j], acc[i][j], 0, 0, 0);
    }

    if (wv >= 2) {
        #pragma unroll
        for (int i = 0; i < 4; i++)
            #pragma unroll
            for (int j = 0; j < 4; j++)
                #pragma unroll
                for (int r = 0; r < 4; r++)
                    racc[wv - 2][i * 16 + lg * 4 + r][j * 16 + lr] = acc[i][j][r];
    }
    __syncthreads();
    if (wv < 2) {
        #pragma unroll
        for (int i = 0; i < 4; i++)
            #pragma unroll
            for (int j = 0; j < 4; j++)
                #pragma unroll
                for (int r = 0; r < 4; r++)
                    racc[wv][i * 16 + lg * 4 + r][j * 16 + lr] += acc[i][j][r];
    }
    __syncthreads();
    float* ub = upart + (size_t)ks * (64 * EDIM);
    #pragma unroll
    for (int q = 0; q < 16; q++) {
        const int idx = q * 256 + tid;
        const int x = idx >> 6, y = idx & 63;
        ub[(size_t)x * EDIM + et * 64 + y] = racc[0][x][y] + racc[1][x][y];
    }
}

// ---------------------------------------------------------------------------
// fin_body: reduce 64 K-partials, 1/||Y3||_F scale, +bias, BN, final L2 norm.
// One block (256 thr) per batch bb; each thread owns e and e+256.
// ---------------------------------------------------------------------------
static __device__ __forceinline__ void fin_body(
    const float* __restrict__ upart, const float* __restrict__ nrmp,
    const float* __restrict__ bias, const float* __restrict__ gma,
    const float* __restrict__ bta, const float* __restrict__ mu,
    const float* __restrict__ var, float* __restrict__ out, int bb, float* wsum)
{
    const int tid = threadIdx.x, wv = tid >> 6, l = tid & 63;
    const int e0 = tid, e1 = tid + 256;
    float u0 = 0.0f, u1 = 0.0f;
    for (int p = 0; p < 64; ++p) {
        const float* up = upart + ((size_t)p * 64 + bb) * EDIM;
        u0 += up[e0]; u1 += up[e1];
    }
    float fro = 0.0f;
    #pragma unroll
    for (int q = 0; q < NTRI; ++q) fro += nrmp[bb * NTRI + q];
    const float s = 1.0f / fmaxf(sqrtf(fro), 1e-12f);
    const float emb0 = s * u0 + bias[e0];
    const float emb1 = s * u1 + bias[e1];
    const float v0 = (emb0 - mu[e0]) * rsqrtf(var[e0] + 1e-5f) * gma[e0] + bta[e0];
    const float v1 = (emb1 - mu[e1]) * rsqrtf(var[e1] + 1e-5f) * gma[e1] + bta[e1];
    float sq = v0 * v0 + v1 * v1;
    #pragma unroll
    for (int o = 32; o >= 1; o >>= 1) sq += __shfl_xor(sq, o, 64);
    if (l == 0) wsum[wv] = sq;
    __syncthreads();
    const float tot = wsum[0] + wsum[1] + wsum[2] + wsum[3];
    const float rn = 1.0f / fmaxf(sqrtf(tot), 1e-12f);
    out[(size_t)bb * EDIM + e0] = v0 * rn;
    out[(size_t)bb * EDIM + e1] = v1 * rn;
}

// ===========================================================================
// Cooperative path
// ===========================================================================
// grid 640, 256 thr; min 4 waves/EU -> VGPR<=128 -> 4 blocks/CU -> capacity
// 1024 >= 640 (round-4 failure: 3-block request quantized to 2 -> 512 < 640).
__global__ __launch_bounds__(256, 4) void k_ns_coop(
    const float* __restrict__ feat, __hip_bfloat16* __restrict__ xcb,
    float* __restrict__ rowsq,
    __hip_bfloat16* __restrict__ M0, __hip_bfloat16* __restrict__ M1,
    __hip_bfloat16* __restrict__ M2, __hip_bfloat16* __restrict__ M3,
    __hip_bfloat16* __restrict__ M4, float* __restrict__ nrmp)
{
    cg::grid_group grid = cg::this_grid();
    __shared__ __hip_bfloat16 As[64][72];
    __shared__ __hip_bfloat16 Bs[64][72];
    __shared__ float red[4];
    __shared__ float s_alpha;

    const int tid = threadIdx.x, wv = tid >> 6, l = tid & 63;

    // phase 0: centering (640 blocks x 4 waves = 2560 rows/iter, 7 iters)
    #pragma unroll
    for (int it = 0; it < 7; ++it) {
        const int row = it * 2560 + blockIdx.x * 4 + wv;
        if (row < BATCH * CDIM) center_row(feat, xcb, rowsq, row, l);
    }
    __threadfence(); grid.sync();

    const int b = blockIdx.x / NTRI;
    const int t = blockIdx.x - b * NTRI;

    // y  = (1/tr) * xc @ xc^T                         -> M0
    mm_tile<MP, false>(xcb, xcb, nullptr, M0, rowsq, 1, 1.0f, 0.0f, 0.0f, nullptr, b, t, As, Bs, red, &s_alpha);
    __threadfence(); grid.sync();
    // Y1 = -0.5*y@y + 1.5*y                           -> M1
    mm_tile<256, false>(M0, M0, M0, M1, nullptr, 0, -0.5f, 1.5f, 0.0f, nullptr, b, t, As, Bs, red, &s_alpha);
    __threadfence(); grid.sync();
    // T2 = 0.5*y@Y1 - 1.5*Y1 + 3I                     -> M2
    mm_tile<256, false>(M0, M1, M1, M2, nullptr, 0, 0.5f, -1.5f, 3.0f, nullptr, b, t, As, Bs, red, &s_alpha);
    __threadfence(); grid.sync();
    // Y2 = 0.5*Y1@T2 -> M3 ; Z2 = -0.25*T2@y + 0.75*T2 -> M4  (same phase)
    mm_tile<256, false>(M1, M2, nullptr, M3, nullptr, 0, 0.5f, 0.0f, 0.0f, nullptr, b, t, As, Bs, red, &s_alpha);
    mm_tile<256, false>(M2, M0, M2, M4, nullptr, 0, -0.25f, 0.75f, 0.0f, nullptr, b, t, As, Bs, red, &s_alpha);
    __threadfence(); grid.sync();
    // T3 = -Z2@Y2 + 3I                                -> M1
    mm_tile<256, false>(M4, M3, nullptr, M1, nullptr, 0, -1.0f, 0.0f, 3.0f, nullptr, b, t, As, Bs, red, &s_alpha);
    __threadfence(); grid.sync();
    // Y3 = 0.5*Y2@T3 (+ Frobenius partials -> nrmp)   -> M2
    mm_tile<256, true>(M3, M1, nullptr, M2, nullptr, 0, 0.5f, 0.0f, 0.0f, nrmp, b, t, As, Bs, red, &s_alpha);
}

// grid 512, 256 thr; min 2 waves/EU -> VGPR<=256 (no spill), 2 blocks/CU.
__global__ __launch_bounds__(256, 2) void k_pf_coop(
    const __hip_bfloat16* __restrict__ flat, const float* __restrict__ W,
    float* __restrict__ upart, const float* __restrict__ nrmp,
    const float* __restrict__ bias, const float* __restrict__ gma,
    const float* __restrict__ bta, const float* __restrict__ mu,
    const float* __restrict__ var, float* __restrict__ out)
{
    cg::grid_group grid = cg::this_grid();
    __shared__ float racc[2][64][65];
    __shared__ float wsum[4];
    proj_body(flat, W, upart, blockIdx.x >> 3, blockIdx.x & 7, racc);
    __threadfence(); grid.sync();
    if (blockIdx.x < BATCH)
        fin_body(upart, nrmp, bias, gma, bta, mu, var, out, blockIdx.x, wsum);
}

// ===========================================================================
// Fallback path (round-3 structure: proven correct, 133 us)
// ===========================================================================
__global__ __launch_bounds__(256) void k_center_f(const float* __restrict__ feat,
                                                  __hip_bfloat16* __restrict__ xcb,
                                                  float* __restrict__ rowsq)
{
    center_row(feat, xcb, rowsq, blockIdx.x * 4 + (threadIdx.x >> 6), threadIdx.x & 63);
}

template<int KT, bool NORM>
__global__ __launch_bounds__(256) void k_mm_f(MMOp op0, MMOp op1)
{
    const MMOp op = (blockIdx.y == 0) ? op0 : op1;
    __shared__ __hip_bfloat16 As[64][72];
    __shared__ __hip_bfloat16 Bs[64][72];
    __shared__ float red[4];
    __shared__ float s_alpha;
    const int b = blockIdx.x / NTRI;
    const int t = blockIdx.x - b * NTRI;
    mm_tile<KT, NORM>(op.A, op.B, op.D, op.out, op.alpha_ptr, op.alpha_mode,
                      op.alpha_c, op.beta, op.gamma, op.nrm, b, t, As, Bs, red, &s_alpha);
}

__global__ __launch_bounds__(256) void k_proj_f(const __hip_bfloat16* __restrict__ flat,
                                                const float* __restrict__ W,
                                                float* __restrict__ upart)
{
    __shared__ float racc[2][64][65];
    proj_body(flat, W, upart, blockIdx.x, blockIdx.y, racc);
}

__global__ __launch_bounds__(256) void k_fin_f(const float* __restrict__ upart,
                                               const float* __restrict__ nrmp,
                                               const float* __restrict__ bias,
                                               const float* __restrict__ gma,
                                               const float* __restrict__ bta,
                                               const float* __restrict__ mu,
                                               const float* __restrict__ var,
                                               float* __restrict__ out)
{
    __shared__ float wsum[4];
    fin_body(upart, nrmp, bias, gma, bta, mu, var, out, blockIdx.x, wsum);
}

// ---------------------------------------------------------------------------
extern "C" void kernel_launch(void* const* d_in, const int* in_sizes, int n_in,
                              void* d_out, int out_size, void* d_ws, size_t ws_size,
                              hipStream_t stream)
{
    const float* feat = (const float*)d_in[0];
    const float* W    = (const float*)d_in[1];
    const float* bias = (const float*)d_in[2];
    const float* gma  = (const float*)d_in[3];
    const float* bta  = (const float*)d_in[4];
    const float* mu   = (const float*)d_in[5];
    const float* var  = (const float*)d_in[6];
    float* out = (float*)d_out;

    char* ws = (char*)d_ws;
    constexpr size_t XCB_BYTES = (size_t)BATCH * CDIM * MP * 2;   // 7,340,032
    constexpr size_t MATB      = (size_t)BATCH * CC * 2;          // 8,388,608
    constexpr size_t OFF_ROWSQ = 4096;
    constexpr size_t OFF_XCB   = OFF_ROWSQ + (size_t)BATCH * CDIM * 4;
    constexpr size_t OFF_M     = OFF_XCB + XCB_BYTES;
    constexpr size_t OFF_UP    = OFF_M + 5 * MATB;
    constexpr size_t NEEDED    = OFF_UP + (size_t)64 * 64 * EDIM * 4;
    if (ws_size < NEEDED) return;   // ~58 MB required

    float* nrmp  = (float*)(ws + 1024);          // 640 floats
    float* rowsq = (float*)(ws + OFF_ROWSQ);     // 16384 floats
    __hip_bfloat16* xcb = (__hip_bfloat16*)(ws + OFF_XCB);
    __hip_bfloat16* M0  = (__hip_bfloat16*)(ws + OFF_M + 0 * MATB);
    __hip_bfloat16* M1  = (__hip_bfloat16*)(ws + OFF_M + 1 * MATB);
    __hip_bfloat16* M2  = (__hip_bfloat16*)(ws + OFF_M + 2 * MATB);
    __hip_bfloat16* M3  = (__hip_bfloat16*)(ws + OFF_M + 3 * MATB);
    __hip_bfloat16* M4  = (__hip_bfloat16*)(ws + OFF_M + 4 * MATB);
    float* upart = (float*)(ws + OFF_UP);

    // ---- capability gate (pure host queries: capture-safe, deterministic) ----
    int dev = 0; hipGetDevice(&dev);
    int coop = 0, ncu = 0;
    hipDeviceGetAttribute(&coop, hipDeviceAttributeCooperativeLaunch, dev);
    hipDeviceGetAttribute(&ncu, hipDeviceAttributeMultiprocessorCount, dev);
    int mb_ns = 0, mb_pf = 0;
    hipOccupancyMaxActiveBlocksPerMultiprocessor(&mb_ns, (const void*)k_ns_coop, 256, 0);
    hipOccupancyMaxActiveBlocksPerMultiprocessor(&mb_pf, (const void*)k_pf_coop, 256, 0);
    bool use_coop = (coop != 0) && ((long)mb_ns * ncu >= BATCH * NTRI)
                                && ((long)mb_pf * ncu >= 512);

    bool coop_done = false;
    if (use_coop) {
        void* argsA[] = {(void*)&feat, (void*)&xcb, (void*)&rowsq,
                         (void*)&M0, (void*)&M1, (void*)&M2, (void*)&M3, (void*)&M4,
                         (void*)&nrmp};
        hipError_t eA = hipLaunchCooperativeKernel((void*)k_ns_coop,
                            dim3(BATCH * NTRI), dim3(256), argsA, 0, stream);
        if (eA == hipSuccess) {
            const __hip_bfloat16* flat = M2;   // Y3
            void* argsB[] = {(void*)&flat, (void*)&W, (void*)&upart, (void*)&nrmp,
                             (void*)&bias, (void*)&gma, (void*)&bta, (void*)&mu,
                             (void*)&var, (void*)&out};
            hipError_t eB = hipLaunchCooperativeKernel((void*)k_pf_coop,
                                dim3(512), dim3(256), argsB, 0, stream);
            if (eB == hipSuccess) {
                coop_done = true;
            } else {
                k_proj_f<<<dim3(64, 8), 256, 0, stream>>>(M2, W, upart);
                k_fin_f<<<dim3(64), 256, 0, stream>>>(upart, nrmp, bias, gma, bta, mu, var, out);
                coop_done = true;
            }
        }
    }

    if (!coop_done) {
        // round-3 proven sequence
        k_center_f<<<dim3(4096), 256, 0, stream>>>(feat, xcb, rowsq);
        const dim3 g1(BATCH * NTRI, 1), g2(BATCH * NTRI, 2), blk(256);
        MMOp nop = {};
        MMOp cov = {xcb, xcb, nullptr, M0, rowsq, 1, 1.0f, 0.0f, 0.0f, nullptr};
        k_mm_f<MP, false><<<g1, blk, 0, stream>>>(cov, nop);
        MMOp y1 = {M0, M0, M0, M1, nullptr, 0, -0.5f, 1.5f, 0.0f, nullptr};
        k_mm_f<256, false><<<g1, blk, 0, stream>>>(y1, nop);
        MMOp t2 = {M0, M1, M1, M2, nullptr, 0, 0.5f, -1.5f, 3.0f, nullptr};
        k_mm_f<256, false><<<g1, blk, 0, stream>>>(t2, nop);
        MMOp y2 = {M1, M2, nullptr, M3, nullptr, 0, 0.5f, 0.0f, 0.0f, nullptr};
        MMOp z2 = {M2, M0, M2, M4, nullptr, 0, -0.25f, 0.75f, 0.0f, nullptr};
        k_mm_f<256, false><<<g2, blk, 0, stream>>>(y2, z2);
        MMOp t3 = {M4, M3, nullptr, M1, nullptr, 0, -1.0f, 0.0f, 3.0f, nullptr};
        k_mm_f<256, false><<<g1, blk, 0, stream>>>(t3, nop);
        MMOp y3 = {M3, M1, nullptr, M2, nullptr, 0, 0.5f, 0.0f, 0.0f, nrmp};
        k_mm_f<256, true ><<<g1, blk, 0, stream>>>(y3, nop);
        k_proj_f<<<dim3(64, 8), 256, 0, stream>>>(M2, W, upart);
        k_fin_f<<<dim3(64), 256, 0, stream>>>(upart, nrmp, bias, gma, bta, mu, var, out);
    }
}